// Round 1
// baseline (155.341 us; speedup 1.0000x reference)
//
#include <hip/hip_runtime.h>
#include <cstddef>

// B=16, N=512, C_SIZE=512, STRIDE=8 -> C=64, M=4096, out [16, 513, 4096] fp32.
constexpr int NPT = 512;
constexpr int C   = 64;
constexpr int M   = C * C;
constexpr int NP1 = NPT + 1;
constexpr float BG_RATIO = 0.15f;
constexpr float EPS = 1e-5f;
// exp(-d/(2*sigma^2)) = exp(-d/128) = exp2(d * NEGK2). Used identically in both
// kernels so numerator/denominator stay bit-consistent.
constexpr float NEGK2 = -0.0112710550069450f;   // -log2(e)/128

typedef float f4 __attribute__((ext_vector_type(4)));

// ---------------------------------------------------------------------------
// Kernel 1: per-pixel softmax denominator.
// Grid (B*64) blocks of 256 threads; block (b, i) handles grid row i (64 px).
// Thread t: jg = t&15 -> pixels j = 4*jg..4*jg+3; pc = t>>4 -> points
// [32*pc, 32*pc+32). Fused min-distance + exp-sum in one pass (logits <= 0 and
// the bg term bounds the denominator away from 0, so no max-shift needed).
// Writes rsw[b][m] = 1/denom (256 KB total, stays L2-hot for kernel 2) and the
// background row of out directly.
// ---------------------------------------------------------------------------
__global__ __launch_bounds__(256) void denom_kernel(
    const float* __restrict__ points,   // [B, NPT, 2] (x, y)
    const float* __restrict__ st,       // [B]
    float* __restrict__ out,            // [B, NP1, M]
    float* __restrict__ rsw)            // [B, M] workspace (1/denominator)
{
    const int b    = blockIdx.x >> 6;
    const int i    = blockIdx.x & 63;
    const int t    = threadIdx.x;
    const int lane = t & 63;
    const int w    = t >> 6;
    const int jg   = t & 15;
    const int pc   = t >> 4;

    const float cy  = (float)(i * 8 + 4);
    const float cx0 = (float)(jg * 32 + 4);
    const float cx1 = cx0 + 8.0f;
    const float cx2 = cx0 + 16.0f;
    const float cx3 = cx0 + 24.0f;

    __shared__ float2 pts[NPT];          // 4 KB
    __shared__ float4 redmin[4][16];     // 1 KB  [wave][jg]
    __shared__ float4 redsum[4][16];     // 1 KB

    const float2* pb = (const float2*)(points + (size_t)b * NPT * 2);
    for (int p = t; p < NPT; p += 256) pts[p] = pb[p];
    __syncthreads();

    const int p0 = pc * 32;

    float4 mn = make_float4(3.4e38f, 3.4e38f, 3.4e38f, 3.4e38f);
    float4 sm = make_float4(0.f, 0.f, 0.f, 0.f);
    #pragma unroll 4
    for (int k = 0; k < 32; ++k) {
        float2 xy = pts[p0 + k];
        float dy  = xy.y - cy;
        float dy2 = dy * dy;
        float dx0 = xy.x - cx0, dx1 = xy.x - cx1, dx2 = xy.x - cx2, dx3 = xy.x - cx3;
        float d0 = fmaf(dx0, dx0, dy2);
        float d1 = fmaf(dx1, dx1, dy2);
        float d2 = fmaf(dx2, dx2, dy2);
        float d3 = fmaf(dx3, dx3, dy2);
        mn.x = fminf(mn.x, d0); mn.y = fminf(mn.y, d1);
        mn.z = fminf(mn.z, d2); mn.w = fminf(mn.w, d3);
        sm.x += exp2f(d0 * NEGK2); sm.y += exp2f(d1 * NEGK2);
        sm.z += exp2f(d2 * NEGK2); sm.w += exp2f(d3 * NEGK2);
    }

    // Reduce over the 4 point-chunks resident in this wave (lane bits 4,5).
    #pragma unroll
    for (int off = 16; off <= 32; off <<= 1) {
        mn.x = fminf(mn.x, __shfl_xor(mn.x, off));
        mn.y = fminf(mn.y, __shfl_xor(mn.y, off));
        mn.z = fminf(mn.z, __shfl_xor(mn.z, off));
        mn.w = fminf(mn.w, __shfl_xor(mn.w, off));
        sm.x += __shfl_xor(sm.x, off);
        sm.y += __shfl_xor(sm.y, off);
        sm.z += __shfl_xor(sm.z, off);
        sm.w += __shfl_xor(sm.w, off);
    }
    if (lane < 16) { redmin[w][lane] = mn; redsum[w][lane] = sm; }
    __syncthreads();

    // Final cross-wave reduce + bg + reciprocal denominator (64 threads).
    if (t < C) {
        const float* rm = (const float*)redmin;   // [4][64] words; word t = pixel j=t
        const float* rq = (const float*)redsum;
        float m0 = fminf(fminf(rm[t], rm[64 + t]), fminf(rm[128 + t], rm[192 + t]));
        float s0 = (rq[t] + rq[64 + t]) + (rq[128 + t] + rq[192 + t]);
        float ss = st[b] * BG_RATIO;
        float bg = (ss * ss) / (m0 + EPS);
        float eb = exp2f(bg * NEGK2);
        float r  = 1.0f / (s0 + eb);
        rsw[(size_t)b * M + i * C + t] = r;
        // Background row (p = NPT): 256 B contiguous per block.
        out[(size_t)b * NP1 * M + (size_t)NPT * M + i * C + t] = eb * r;
    }
}

// ---------------------------------------------------------------------------
// Kernel 2: the 134 MB write, restructured for DRAM page locality.
// Grid (B*64) blocks of 256 threads; block (b, pch) owns points
// p = 8*pch..8*pch+7 and writes 8 complete 16 KB output rows = 128 KB of
// FULLY SEQUENTIAL address space (vs. the old 256 B-every-16 KB scatter that
// page-thrashed the write stream to ~37% efficiency).
// rs tile (16 KB per image, reused by 64 blocks) is read from L2 into
// registers; stores are nontemporal so the streaming output doesn't evict it.
// ---------------------------------------------------------------------------
__global__ __launch_bounds__(256) void write_kernel(
    const float* __restrict__ points,   // [B, NPT, 2]
    const float* __restrict__ rsw,      // [B, M]
    float* __restrict__ out)            // [B, NP1, M]
{
    const int b   = blockIdx.x >> 6;
    const int pch = blockIdx.x & 63;
    const int t   = threadIdx.x;

    // Per-pass geometry + 1/denom, held in registers across all 8 point rows.
    // pass q: this thread owns pixels m = 4*(q*256 + t) .. +3  (same grid row i).
    float cyv[4], cxv[4];
    f4 r4[4];
    #pragma unroll
    for (int q = 0; q < 4; ++q) {
        int m4 = (q * 256 + t) * 4;
        cyv[q] = (float)((m4 >> 6) * 8 + 4);
        cxv[q] = (float)((m4 & 63) * 8 + 4);
        r4[q]  = *(const f4*)(rsw + (size_t)b * M + m4);
    }

    const float2* pb = (const float2*)(points + (size_t)b * NPT * 2) + pch * 8;
    float* ob = out + (size_t)b * NP1 * M + (size_t)(pch * 8) * M + t * 4;

    #pragma unroll 2
    for (int p = 0; p < 8; ++p) {
        const float x = pb[p].x;          // uniform -> scalar loads, L2-hot
        const float y = pb[p].y;
        float* op = ob + (size_t)p * M;
        #pragma unroll
        for (int q = 0; q < 4; ++q) {
            float dy  = y - cyv[q];
            float dy2 = dy * dy;
            float dx0 = x - cxv[q];
            float dx1 = dx0 - 8.0f, dx2 = dx0 - 16.0f, dx3 = dx0 - 24.0f;
            f4 v;
            v.x = exp2f(fmaf(dx0, dx0, dy2) * NEGK2) * r4[q].x;
            v.y = exp2f(fmaf(dx1, dx1, dy2) * NEGK2) * r4[q].y;
            v.z = exp2f(fmaf(dx2, dx2, dy2) * NEGK2) * r4[q].z;
            v.w = exp2f(fmaf(dx3, dx3, dy2) * NEGK2) * r4[q].w;
            __builtin_nontemporal_store(v, (f4*)(op + q * 1024));
        }
    }
}

extern "C" void kernel_launch(void* const* d_in, const int* in_sizes, int n_in,
                              void* d_out, int out_size, void* d_ws, size_t ws_size,
                              hipStream_t stream) {
    const float* points = (const float*)d_in[0];   // [16, 512, 2] fp32
    const float* st     = (const float*)d_in[1];   // [16] fp32
    float* out          = (float*)d_out;           // [16, 513, 4096] fp32
    float* rsw          = (float*)d_ws;            // needs B*M*4 = 256 KB

    const int B = in_sizes[1];                     // 16
    denom_kernel<<<dim3(B * C), dim3(256), 0, stream>>>(points, st, out, rsw);
    write_kernel<<<dim3(B * C), dim3(256), 0, stream>>>(points, rsw, out);
}

// Round 2
// 147.744 us; speedup vs baseline: 1.0514x; 1.0514x over previous
//
#include <hip/hip_runtime.h>
#include <cstddef>

// B=16, N=512, C_SIZE=512, STRIDE=8 -> C=64, M=4096, out [16, 513, 4096] fp32.
constexpr int NPT = 512;
constexpr int C   = 64;
constexpr int M   = C * C;
constexpr int NP1 = NPT + 1;
constexpr float BG_RATIO = 0.15f;
constexpr float EPS = 1e-5f;
// exp(-d/(2*sigma^2)) = exp(-d/128) = exp2(d * NEGK2). Used identically in both
// kernels so numerator/denominator stay bit-consistent.
constexpr float NEGK2 = -0.0112710550069450f;   // -log2(e)/128

typedef float f4 __attribute__((ext_vector_type(4)));

// ---------------------------------------------------------------------------
// Kernel 1: per-pixel softmax denominator.
// Grid (B*64) blocks of 256 threads; block (b, i) handles grid row i (64 px).
// Thread t: jg = t&15 -> pixels j = 4*jg..4*jg+3; pc = t>>4 -> points
// [32*pc, 32*pc+32). Fused min-distance + exp-sum in one pass (logits <= 0 and
// the bg term bounds the denominator away from 0, so no max-shift needed).
// Writes rsw[b][m] = 1/denom (256 KB total, stays L2-hot for kernel 2) and the
// background row of out directly.
// ---------------------------------------------------------------------------
__global__ __launch_bounds__(256) void denom_kernel(
    const float* __restrict__ points,   // [B, NPT, 2] (x, y)
    const float* __restrict__ st,       // [B]
    float* __restrict__ out,            // [B, NP1, M]
    float* __restrict__ rsw)            // [B, M] workspace (1/denominator)
{
    const int b    = blockIdx.x >> 6;
    const int i    = blockIdx.x & 63;
    const int t    = threadIdx.x;
    const int lane = t & 63;
    const int w    = t >> 6;
    const int jg   = t & 15;
    const int pc   = t >> 4;

    const float cy  = (float)(i * 8 + 4);
    const float cx0 = (float)(jg * 32 + 4);
    const float cx1 = cx0 + 8.0f;
    const float cx2 = cx0 + 16.0f;
    const float cx3 = cx0 + 24.0f;

    __shared__ float2 pts[NPT];          // 4 KB
    __shared__ float4 redmin[4][16];     // 1 KB  [wave][jg]
    __shared__ float4 redsum[4][16];     // 1 KB

    const float2* pb = (const float2*)(points + (size_t)b * NPT * 2);
    for (int p = t; p < NPT; p += 256) pts[p] = pb[p];
    __syncthreads();

    const int p0 = pc * 32;

    float4 mn = make_float4(3.4e38f, 3.4e38f, 3.4e38f, 3.4e38f);
    float4 sm = make_float4(0.f, 0.f, 0.f, 0.f);
    #pragma unroll 4
    for (int k = 0; k < 32; ++k) {
        float2 xy = pts[p0 + k];
        float dy  = xy.y - cy;
        float dy2 = dy * dy;
        float dx0 = xy.x - cx0, dx1 = xy.x - cx1, dx2 = xy.x - cx2, dx3 = xy.x - cx3;
        float d0 = fmaf(dx0, dx0, dy2);
        float d1 = fmaf(dx1, dx1, dy2);
        float d2 = fmaf(dx2, dx2, dy2);
        float d3 = fmaf(dx3, dx3, dy2);
        mn.x = fminf(mn.x, d0); mn.y = fminf(mn.y, d1);
        mn.z = fminf(mn.z, d2); mn.w = fminf(mn.w, d3);
        sm.x += exp2f(d0 * NEGK2); sm.y += exp2f(d1 * NEGK2);
        sm.z += exp2f(d2 * NEGK2); sm.w += exp2f(d3 * NEGK2);
    }

    // Reduce over the 4 point-chunks resident in this wave (lane bits 4,5).
    #pragma unroll
    for (int off = 16; off <= 32; off <<= 1) {
        mn.x = fminf(mn.x, __shfl_xor(mn.x, off));
        mn.y = fminf(mn.y, __shfl_xor(mn.y, off));
        mn.z = fminf(mn.z, __shfl_xor(mn.z, off));
        mn.w = fminf(mn.w, __shfl_xor(mn.w, off));
        sm.x += __shfl_xor(sm.x, off);
        sm.y += __shfl_xor(sm.y, off);
        sm.z += __shfl_xor(sm.z, off);
        sm.w += __shfl_xor(sm.w, off);
    }
    if (lane < 16) { redmin[w][lane] = mn; redsum[w][lane] = sm; }
    __syncthreads();

    // Final cross-wave reduce + bg + reciprocal denominator (64 threads).
    if (t < C) {
        const float* rm = (const float*)redmin;   // [4][64] words; word t = pixel j=t
        const float* rq = (const float*)redsum;
        float m0 = fminf(fminf(rm[t], rm[64 + t]), fminf(rm[128 + t], rm[192 + t]));
        float s0 = (rq[t] + rq[64 + t]) + (rq[128 + t] + rq[192 + t]);
        float ss = st[b] * BG_RATIO;
        float bg = (ss * ss) / (m0 + EPS);
        float eb = exp2f(bg * NEGK2);
        float r  = 1.0f / (s0 + eb);
        rsw[(size_t)b * M + i * C + t] = r;
        // Background row (p = NPT): 256 B contiguous per block.
        out[(size_t)b * NP1 * M + (size_t)NPT * M + i * C + t] = eb * r;
    }
}

// ---------------------------------------------------------------------------
// Kernel 2: the 134 MB write, restructured for DRAM page locality.
// Grid (B*64) blocks of 256 threads; block (b, pch) owns points
// p = 8*pch..8*pch+7 and writes 8 complete 16 KB output rows = 128 KB of
// FULLY SEQUENTIAL address space. PLAIN cached stores this round: round 1's
// nontemporal stores bypassed L2 while L2 held dirty poison-fill lines for
// these exact addresses — suspected coherence-probe serialization that
// negated the sequential-address win. The harness fill itself sustains
// 6.1-6.6 TB/s with cached stores on this very buffer.
// ---------------------------------------------------------------------------
__global__ __launch_bounds__(256) void write_kernel(
    const float* __restrict__ points,   // [B, NPT, 2]
    const float* __restrict__ rsw,      // [B, M]
    float* __restrict__ out)            // [B, NP1, M]
{
    const int b   = blockIdx.x >> 6;
    const int pch = blockIdx.x & 63;
    const int t   = threadIdx.x;

    // Per-pass geometry + 1/denom, held in registers across all 8 point rows.
    // pass q: this thread owns pixels m = 4*(q*256 + t) .. +3  (same grid row i).
    float cyv[4], cxv[4];
    f4 r4[4];
    #pragma unroll
    for (int q = 0; q < 4; ++q) {
        int m4 = (q * 256 + t) * 4;
        cyv[q] = (float)((m4 >> 6) * 8 + 4);
        cxv[q] = (float)((m4 & 63) * 8 + 4);
        r4[q]  = *(const f4*)(rsw + (size_t)b * M + m4);
    }

    const float2* pb = (const float2*)(points + (size_t)b * NPT * 2) + pch * 8;
    float* ob = out + (size_t)b * NP1 * M + (size_t)(pch * 8) * M + t * 4;

    #pragma unroll 2
    for (int p = 0; p < 8; ++p) {
        const float x = pb[p].x;          // uniform -> scalar loads, L2-hot
        const float y = pb[p].y;
        float* op = ob + (size_t)p * M;
        #pragma unroll
        for (int q = 0; q < 4; ++q) {
            float dy  = y - cyv[q];
            float dy2 = dy * dy;
            float dx0 = x - cxv[q];
            float dx1 = dx0 - 8.0f, dx2 = dx0 - 16.0f, dx3 = dx0 - 24.0f;
            f4 v;
            v.x = exp2f(fmaf(dx0, dx0, dy2) * NEGK2) * r4[q].x;
            v.y = exp2f(fmaf(dx1, dx1, dy2) * NEGK2) * r4[q].y;
            v.z = exp2f(fmaf(dx2, dx2, dy2) * NEGK2) * r4[q].z;
            v.w = exp2f(fmaf(dx3, dx3, dy2) * NEGK2) * r4[q].w;
            *(f4*)(op + q * 1024) = v;
        }
    }
}

extern "C" void kernel_launch(void* const* d_in, const int* in_sizes, int n_in,
                              void* d_out, int out_size, void* d_ws, size_t ws_size,
                              hipStream_t stream) {
    const float* points = (const float*)d_in[0];   // [16, 512, 2] fp32
    const float* st     = (const float*)d_in[1];   // [16] fp32
    float* out          = (float*)d_out;           // [16, 513, 4096] fp32
    float* rsw          = (float*)d_ws;            // needs B*M*4 = 256 KB

    const int B = in_sizes[1];                     // 16
    denom_kernel<<<dim3(B * C), dim3(256), 0, stream>>>(points, st, out, rsw);
    write_kernel<<<dim3(B * C), dim3(256), 0, stream>>>(points, rsw, out);
}

// Round 3
// 141.873 us; speedup vs baseline: 1.0949x; 1.0414x over previous
//
#include <hip/hip_runtime.h>
#include <cstddef>

// B=16, N=512, C_SIZE=512, STRIDE=8 -> C=64, M=4096, out [16, 513, 4096] fp32.
constexpr int NPT = 512;
constexpr int C   = 64;
constexpr int M   = C * C;
constexpr int NP1 = NPT + 1;
constexpr float BG_RATIO = 0.15f;
constexpr float EPS = 1e-5f;
// exp(-d/(2*sigma^2)) = exp(-d/128) = exp2(d * NEGK2); log2-domain constant
// saves one v_mul per exp vs __expf (validated rounds 1-2, absmax unchanged).
constexpr float NEGK2 = -0.0112710550069450f;   // -log2(e)/128

typedef float f4 __attribute__((ext_vector_type(4)));

// Fused single kernel (round-0 structure, which beat the 2-kernel split by
// ~7 us at equal clocks). Changes vs round 0:
//  - ONE barrier after the reduction instead of two: the cross-wave reduce +
//    bg + reciprocal epilogue is done redundantly by every wave from LDS
//    (8 conflict-free reads + ~30 VALU + 4 shuffles) instead of by a serial
//    t<64 section that idled 192 threads between two __syncthreads.
//  - exp2f(d*NEGK2) instead of __expf(-d*K) in all three places.
//  - unroll 8 on the store pass for trans/VMEM ILP.
// Block = 256 threads = 4 waves per (b, i) grid row.
// Thread t: jg = t&15 -> pixels j = 4*jg..4*jg+3; pc = t>>4 -> points
// [32*pc, 32*pc+32). No max-shift needed: logits <= 0 and the bg term bounds
// the softmax denominator away from 0.
__global__ __launch_bounds__(256) void pp_kernel(
    const float* __restrict__ points,   // [B, NPT, 2] (x, y)
    const float* __restrict__ st,       // [B]
    float* __restrict__ out)            // [B, NP1, M]
{
    const int b    = blockIdx.x >> 6;
    const int i    = blockIdx.x & 63;
    const int t    = threadIdx.x;
    const int lane = t & 63;
    const int w    = t >> 6;
    const int jg   = t & 15;
    const int pc   = t >> 4;

    const float cy  = (float)(i * 8 + 4);
    const float cx0 = (float)(jg * 32 + 4);
    const float cx1 = cx0 + 8.0f;
    const float cx2 = cx0 + 16.0f;
    const float cx3 = cx0 + 24.0f;

    __shared__ float2 pts[NPT];          // 4 KB
    __shared__ float  redmin[4][64];     // 1 KB  [wave][pixel]
    __shared__ float  redsum[4][64];     // 1 KB

    const float2* pb = (const float2*)(points + (size_t)b * NPT * 2);
    for (int p = t; p < NPT; p += 256) pts[p] = pb[p];
    __syncthreads();

    const int p0 = pc * 32;

    // ---- Pass 1: fused min-distance + exp-sum over this 32-point chunk ----
    float4 mn = make_float4(3.4e38f, 3.4e38f, 3.4e38f, 3.4e38f);
    float4 sm = make_float4(0.f, 0.f, 0.f, 0.f);
    #pragma unroll 8
    for (int k = 0; k < 32; ++k) {
        float2 xy = pts[p0 + k];
        float dy  = xy.y - cy;
        float dy2 = dy * dy;
        float dx0 = xy.x - cx0, dx1 = xy.x - cx1, dx2 = xy.x - cx2, dx3 = xy.x - cx3;
        float d0 = fmaf(dx0, dx0, dy2);
        float d1 = fmaf(dx1, dx1, dy2);
        float d2 = fmaf(dx2, dx2, dy2);
        float d3 = fmaf(dx3, dx3, dy2);
        mn.x = fminf(mn.x, d0); mn.y = fminf(mn.y, d1);
        mn.z = fminf(mn.z, d2); mn.w = fminf(mn.w, d3);
        sm.x += exp2f(d0 * NEGK2); sm.y += exp2f(d1 * NEGK2);
        sm.z += exp2f(d2 * NEGK2); sm.w += exp2f(d3 * NEGK2);
    }

    // Reduce over the 4 point-chunks resident in this wave (lane bits 4,5).
    #pragma unroll
    for (int off = 16; off <= 32; off <<= 1) {
        mn.x = fminf(mn.x, __shfl_xor(mn.x, off));
        mn.y = fminf(mn.y, __shfl_xor(mn.y, off));
        mn.z = fminf(mn.z, __shfl_xor(mn.z, off));
        mn.w = fminf(mn.w, __shfl_xor(mn.w, off));
        sm.x += __shfl_xor(sm.x, off);
        sm.y += __shfl_xor(sm.y, off);
        sm.z += __shfl_xor(sm.z, off);
        sm.w += __shfl_xor(sm.w, off);
    }
    if (lane < 16) {
        *(float4*)&redmin[w][lane * 4] = mn;   // word 4*jg+q = pixel j
        *(float4*)&redsum[w][lane * 4] = sm;
    }
    __syncthreads();   // the ONLY post-load barrier

    // ---- Epilogue, redundant per wave: lane px = pixel px of this row ----
    const float* rm = (const float*)redmin;   // [4][64] words
    const float* rq = (const float*)redsum;
    float m0 = fminf(fminf(rm[lane], rm[64 + lane]),
                     fminf(rm[128 + lane], rm[192 + lane]));
    float s0 = (rq[lane] + rq[64 + lane]) + (rq[128 + lane] + rq[192 + lane]);
    float ss = st[b] * BG_RATIO;
    float bg = (ss * ss) / (m0 + EPS);
    float eb = exp2f(bg * NEGK2);
    float r  = 1.0f / (s0 + eb);
    if (w == 0) {   // background row (p = NPT): 256 B contiguous per block
        out[(size_t)b * NP1 * M + (size_t)NPT * M + i * C + lane] = eb * r;
    }
    // Gather 1/denom for my 4 pixels (4*jg..4*jg+3) from the wave.
    const int jb = (lane & 15) << 2;
    float r0 = __shfl(r, jb);
    float r1 = __shfl(r, jb + 1);
    float r2 = __shfl(r, jb + 2);
    float r3 = __shfl(r, jb + 3);

    // ---- Pass 2: recompute exp, normalize, float4 stream out ----
    float* ob = out + (size_t)b * NP1 * M + (size_t)p0 * M + i * C + jg * 4;
    #pragma unroll 8
    for (int k = 0; k < 32; ++k) {
        float2 xy = pts[p0 + k];
        float dy  = xy.y - cy;
        float dy2 = dy * dy;
        float dx0 = xy.x - cx0, dx1 = xy.x - cx1, dx2 = xy.x - cx2, dx3 = xy.x - cx3;
        f4 v;
        v.x = exp2f(fmaf(dx0, dx0, dy2) * NEGK2) * r0;
        v.y = exp2f(fmaf(dx1, dx1, dy2) * NEGK2) * r1;
        v.z = exp2f(fmaf(dx2, dx2, dy2) * NEGK2) * r2;
        v.w = exp2f(fmaf(dx3, dx3, dy2) * NEGK2) * r3;
        *(f4*)(ob + (size_t)k * M) = v;
    }
}

extern "C" void kernel_launch(void* const* d_in, const int* in_sizes, int n_in,
                              void* d_out, int out_size, void* d_ws, size_t ws_size,
                              hipStream_t stream) {
    const float* points = (const float*)d_in[0];   // [16, 512, 2] fp32
    const float* st     = (const float*)d_in[1];   // [16] fp32
    float* out          = (float*)d_out;           // [16, 513, 4096] fp32

    const int B = in_sizes[1];                     // 16
    dim3 grid(B * C);                              // 1024 blocks: (b*64 + i)
    dim3 block(256);
    pp_kernel<<<grid, block, 0, stream>>>(points, st, out);
}